// Round 6
// baseline (96.476 us; speedup 1.0000x reference)
//
#include <hip/hip_runtime.h>

#define BB 4
#define SS 4096
#define DD 64
// scale = 1/sqrt(4096), with log2(e) folded in so softmax runs in exp2 domain
#define QSCALE (0.015625f * 1.44269504088896f)

typedef __attribute__((ext_vector_type(4))) float f32x4;
typedef __attribute__((ext_vector_type(8))) short s16x8;
typedef unsigned short u16;

union frag_u { unsigned u[4]; s16x8 s; };

// Partial slot: 16x64 o + 16 m + 16 l = 1056 f32 (4224 B, 16B-aligned stride)
#define SLOT_F 1056

// Round-half-up pack of two f32 into (lo,hi) bf16 pair: 2 v_add + 1 v_perm.
__device__ __forceinline__ unsigned pack_bf16(float lo, float hi) {
    union { float f; unsigned u; } a, b; a.f = lo; b.f = hi;
    return __builtin_amdgcn_perm(b.u + 0x8000u, a.u + 0x8000u, 0x07060302u);
}

// ---- prep 1: K (fp32 row-major) -> Kbf (bf16 row-major) ----
__global__ __launch_bounds__(256) void conv_k(const float* __restrict__ K,
                                              u16* __restrict__ Kbf) {
    const long i = ((long)blockIdx.x * 256 + threadIdx.x) * 8;
    f32x4 a = *(const f32x4*)(K + i);
    f32x4 b = *(const f32x4*)(K + i + 4);
    frag_u f;
    f.u[0] = pack_bf16(a[0], a[1]);
    f.u[1] = pack_bf16(a[2], a[3]);
    f.u[2] = pack_bf16(b[0], b[1]);
    f.u[3] = pack_bf16(b[2], b[3]);
    *(s16x8*)(Kbf + i) = f.s;
}

// ---- prep 2: V (fp32 [b][s][d]) -> VT (bf16 [b][d][s]) ----
__global__ __launch_bounds__(256) void conv_vt(const float* __restrict__ V,
                                               u16* __restrict__ VT) {
    __shared__ u16 tile[64][72];
    const int b  = blockIdx.x >> 6;
    const int kt = blockIdx.x & 63;
    const int tid = threadIdx.x;
    const float* Vb = V + ((long)b * SS + kt * 64) * DD;
    {
        const int kk = tid >> 4;
        const int d4 = (tid & 15) * 4;
        #pragma unroll
        for (int p = 0; p < 4; ++p) {
            const int k = kk + p * 16;
            f32x4 v = *(const f32x4*)(Vb + k * DD + d4);
            #pragma unroll
            for (int c = 0; c < 4; ++c) {
                union { float f; unsigned u; } x; x.f = v[c];
                tile[d4 + c][k] = (u16)((x.u + 0x8000u) >> 16);
            }
        }
    }
    __syncthreads();
    {
        const int d  = tid >> 2;
        const int kg = (tid & 3) * 16;
        u16* dst = VT + ((long)b * DD + d) * SS + kt * 64 + kg;
        frag_u w0, w1;
        #pragma unroll
        for (int j = 0; j < 4; ++j) {
            w0.u[j] = (unsigned)tile[d][kg + 2 * j] | ((unsigned)tile[d][kg + 2 * j + 1] << 16);
            w1.u[j] = (unsigned)tile[d][kg + 8 + 2 * j] | ((unsigned)tile[d][kg + 9 + 2 * j] << 16);
        }
        *(s16x8*)dst = w0.s;
        *(s16x8*)(dst + 8) = w1.s;
    }
}

// ================= Phase 1: partial flash over a KV chunk (<=16 tiles) ======
// idx = ((c*256)+t)*4 + b ; chunk c covers tiles [c*16, c*16+16); wave w takes
// tiles c*16+w, c*16+8+w  ->  <=2 serial tiles per wave.
__global__ __launch_bounds__(512, 4) void
attn_part(const float* __restrict__ Q, const u16* __restrict__ Kbf,
          const u16* __restrict__ VT, float* __restrict__ part)
{
    const int idx = blockIdx.x;
    const int b = idx & 3;
    const int t = (idx >> 2) & 255;
    const int c = idx >> 10;
    const int ntiles = (t >> 2) + 1;
    const int nch = (t >> 6) + 1;          // ceil(ntiles/16)
    if (c >= nch) return;                  // uniform exit, before any barrier

    __shared__ float mbuf[4][16 * 68];
    __shared__ float smM[4][16];
    __shared__ float smL[4][16];

    const int tid  = threadIdx.x;
    const int w    = tid >> 6;
    const int lane = tid & 63;
    const int m    = lane & 15;
    const int g    = lane >> 4;
    const int q0   = t * 16;

    const u16* Kf0 = Kbf + ((long)b * SS) * DD + g * 8;
    const u16* Vt0 = VT + (long)b * DD * SS + (long)m * SS + g * 8;

    // ---- Q fragments (B operand of swapped QK^T), scale folded in ----
    s16x8 qf[2];
    {
        const float* qrow = Q + ((long)b * SS + q0 + m) * DD + g * 8;
        #pragma unroll
        for (int kst = 0; kst < 2; ++kst) {
            f32x4 x0 = *(const f32x4*)(qrow + kst * 32);
            f32x4 x1 = *(const f32x4*)(qrow + kst * 32 + 4);
            frag_u f;
            f.u[0] = pack_bf16(x0[0] * QSCALE, x0[1] * QSCALE);
            f.u[1] = pack_bf16(x0[2] * QSCALE, x0[3] * QSCALE);
            f.u[2] = pack_bf16(x1[0] * QSCALE, x1[1] * QSCALE);
            f.u[3] = pack_bf16(x1[2] * QSCALE, x1[3] * QSCALE);
            qf[kst] = f.s;
        }
    }

    f32x4 o[4];
    #pragma unroll
    for (int dt = 0; dt < 4; ++dt) o[dt] = (f32x4){0.f, 0.f, 0.f, 0.f};
    float m_run = -1e30f, l_run = 0.f;

    const int q_g = q0 + m;
    const int hi  = min(ntiles, c * 16 + 16);

    for (int tile = c * 16 + w; tile < hi; tile += 8) {
        const int kvbase = tile * 64;

        // ---- batch K and V fragment loads ----
        s16x8 kf[4][2];
        const u16* kr0 = Kf0 + (long)(kvbase + m) * DD;
        #pragma unroll
        for (int mt = 0; mt < 4; ++mt)
            #pragma unroll
            for (int kst = 0; kst < 2; ++kst)
                kf[mt][kst] = *(const s16x8*)(kr0 + mt * 16 * DD + kst * 32);
        s16x8 vf[2][4];
        const u16* vr0 = Vt0 + kvbase;
        #pragma unroll
        for (int kst = 0; kst < 2; ++kst)
            #pragma unroll
            for (int dt = 0; dt < 4; ++dt)
                vf[kst][dt] = *(const s16x8*)(vr0 + (long)dt * 16 * SS + kst * 32);

        // ---- S^T = K_tile · Q^T ----
        f32x4 st[4];
        #pragma unroll
        for (int mt = 0; mt < 4; ++mt) {
            st[mt] = (f32x4){0.f, 0.f, 0.f, 0.f};
            #pragma unroll
            for (int kst = 0; kst < 2; ++kst)
                st[mt] = __builtin_amdgcn_mfma_f32_16x16x32_bf16(kf[mt][kst], qf[kst], st[mt], 0, 0, 0);
        }

        // ---- causal mask (diagonal tile only) ----
        if (tile == ntiles - 1) {
            #pragma unroll
            for (int mt = 0; mt < 4; ++mt)
                #pragma unroll
                for (int r = 0; r < 4; ++r) {
                    const int k_g = kvbase + mt * 16 + g * 4 + r;
                    if (k_g > q_g) st[mt][r] = -1e9f;
                }
        }

        // ---- online softmax (exp2 domain); lane owns row q0+m ----
        float tm = st[0][0];
        #pragma unroll
        for (int mt = 0; mt < 4; ++mt)
            #pragma unroll
            for (int r = 0; r < 4; ++r) tm = fmaxf(tm, st[mt][r]);
        tm = fmaxf(tm, __shfl_xor(tm, 16));
        tm = fmaxf(tm, __shfl_xor(tm, 32));
        const float mnew  = fmaxf(m_run, tm);
        const float alpha = exp2f(m_run - mnew);
        float rs = 0.f;
        #pragma unroll
        for (int mt = 0; mt < 4; ++mt)
            #pragma unroll
            for (int r = 0; r < 4; ++r) {
                const float e = exp2f(st[mt][r] - mnew);
                st[mt][r] = e;
                rs += e;
            }
        rs += __shfl_xor(rs, 16);
        rs += __shfl_xor(rs, 32);
        l_run = l_run * alpha + rs;
        m_run = mnew;

        unsigned pk[4][2];
        #pragma unroll
        for (int mt = 0; mt < 4; ++mt) {
            pk[mt][0] = pack_bf16(st[mt][0], st[mt][1]);
            pk[mt][1] = pack_bf16(st[mt][2], st[mt][3]);
        }

        float av[4];
        #pragma unroll
        for (int r = 0; r < 4; ++r) av[r] = __shfl(alpha, 4 * g + r);
        #pragma unroll
        for (int dt = 0; dt < 4; ++dt)
            #pragma unroll
            for (int r = 0; r < 4; ++r) o[dt][r] *= av[r];

        // ---- O += P · V (A via 2-shfl relayout, dest-side select) ----
        #pragma unroll
        for (int kst = 0; kst < 2; ++kst) {
            frag_u pa;
            #pragma unroll
            for (int ww = 0; ww < 4; ++ww) {
                const int srcl = m + 16 * (2 * (g & 1) + (ww >> 1));
                const int v0 = __shfl((int)pk[2 * kst][ww & 1], srcl);
                const int v1 = __shfl((int)pk[2 * kst + 1][ww & 1], srcl);
                pa.u[ww] = (unsigned)((g & 2) ? v1 : v0);
            }
            #pragma unroll
            for (int dt = 0; dt < 4; ++dt)
                o[dt] = __builtin_amdgcn_mfma_f32_16x16x32_bf16(pa.s, vf[kst][dt], o[dt], 0, 0, 0);
        }
    }

    // ---- merge tree across the 8 waves ----
    for (int half = 4; half >= 1; half >>= 1) {
        if (w >= half && w < 2 * half) {
            const int slot = w - half;
            if (g == 0) { smM[slot][m] = m_run; smL[slot][m] = l_run; }
            #pragma unroll
            for (int dt = 0; dt < 4; ++dt)
                #pragma unroll
                for (int r = 0; r < 4; ++r)
                    mbuf[slot][(4 * g + r) * 68 + 16 * dt + m] = o[dt][r];
        }
        __syncthreads();
        if (w < half) {
            const float m2 = smM[w][m], l2 = smL[w][m];
            const float mn = fmaxf(m_run, m2);
            const float a1 = exp2f(m_run - mn);
            const float a2 = exp2f(m2 - mn);
            l_run = l_run * a1 + l2 * a2;
            m_run = mn;
            float av1[4], av2[4];
            #pragma unroll
            for (int r = 0; r < 4; ++r) {
                av1[r] = __shfl(a1, 4 * g + r);
                av2[r] = __shfl(a2, 4 * g + r);
            }
            #pragma unroll
            for (int dt = 0; dt < 4; ++dt)
                #pragma unroll
                for (int r = 0; r < 4; ++r)
                    o[dt][r] = o[dt][r] * av1[r] +
                               mbuf[w][(4 * g + r) * 68 + 16 * dt + m] * av2[r];
        }
        __syncthreads();
    }

    // ---- write unnormalized partial (o, m, l) ----
    if (w == 0) {
        float* P = part + (long)idx * SLOT_F;
        #pragma unroll
        for (int dt = 0; dt < 4; ++dt)
            #pragma unroll
            for (int r = 0; r < 4; ++r)
                P[(4 * g + r) * 64 + dt * 16 + m] = o[dt][r];
        if (g == 0) { P[1024 + m] = m_run; P[1040 + m] = l_run; }
    }
}

// ================= Phase 2: merge <=4 partials per strip, normalize =========
__global__ __launch_bounds__(256) void
attn_merge(const float* __restrict__ part, float* __restrict__ O)
{
    const int bid = blockIdx.x;          // (b,t): bid = b*256 + t ... use t major
    const int b = bid & 3;
    const int t = bid >> 2;
    const int nch = (t >> 6) + 1;
    const int tid = threadIdx.x;
    const int r  = tid >> 4;
    const int c4 = (tid & 15) * 4;

    float mv[4], lv[4];
    float mstar = -1e30f;
    for (int i = 0; i < nch; ++i) {
        const long slot = ((long)(i * 256 + t) * 4 + b) * SLOT_F;
        mv[i] = part[slot + 1024 + r];
        lv[i] = part[slot + 1040 + r];
        mstar = fmaxf(mstar, mv[i]);
    }
    f32x4 acc = (f32x4){0.f, 0.f, 0.f, 0.f};
    float lsum = 0.f;
    for (int i = 0; i < nch; ++i) {
        const long slot = ((long)(i * 256 + t) * 4 + b) * SLOT_F;
        const float wgt = exp2f(mv[i] - mstar);
        f32x4 ov = *(const f32x4*)(part + slot + r * 64 + c4);
        acc += wgt * ov;
        lsum += wgt * lv[i];
    }
    const float inv = 1.0f / lsum;
    *(f32x4*)(O + ((long)b * SS + t * 16 + r) * DD + c4) = acc * inv;
}

// ================= Fallback: round-5 mono kernel ============================
template<bool PRE>
__global__ __launch_bounds__(512, 4) void
attn_fwd(const float* __restrict__ Q, const float* __restrict__ K,
         const float* __restrict__ V, float* __restrict__ O,
         const u16* __restrict__ Kbf, const u16* __restrict__ VT)
{
    __shared__ float mbuf[4][16 * 68];
    __shared__ float smM[4][16];
    __shared__ float smL[4][16];

    const int tid  = threadIdx.x;
    const int w    = tid >> 6;
    const int lane = tid & 63;
    const int m    = lane & 15;
    const int g    = lane >> 4;

    const int idx = blockIdx.x;
    const int t   = 255 - (idx >> 2);
    const int b   = idx & 3;
    const int q0  = t * 16;

    const float* Qb  = Q + ((long)b * SS + q0) * DD;
    const float* Kb0 = K + (long)b * SS * DD;
    const float* Vb0 = V + (long)b * SS * DD;
    const u16* Kf0 = Kbf + ((long)b * SS) * DD + g * 8;
    const u16* Vt0 = VT + (long)b * DD * SS + (long)m * SS + g * 8;

    s16x8 qf[2];
    {
        const float* qrow = Qb + m * DD + g * 8;
        #pragma unroll
        for (int kst = 0; kst < 2; ++kst) {
            f32x4 x0 = *(const f32x4*)(qrow + kst * 32);
            f32x4 x1 = *(const f32x4*)(qrow + kst * 32 + 4);
            frag_u f;
            f.u[0] = pack_bf16(x0[0] * QSCALE, x0[1] * QSCALE);
            f.u[1] = pack_bf16(x0[2] * QSCALE, x0[3] * QSCALE);
            f.u[2] = pack_bf16(x1[0] * QSCALE, x1[1] * QSCALE);
            f.u[3] = pack_bf16(x1[2] * QSCALE, x1[3] * QSCALE);
            qf[kst] = f.s;
        }
    }

    f32x4 o[4];
    #pragma unroll
    for (int dt = 0; dt < 4; ++dt) o[dt] = (f32x4){0.f, 0.f, 0.f, 0.f};
    float m_run = -1e30f, l_run = 0.f;

    const int ntiles = (q0 >> 6) + 1;
    const int q_g = q0 + m;

    for (int tile = w; tile < ntiles; tile += 8) {
        const int kvbase = tile * 64;
        f32x4 st[4];
        if (PRE) {
            s16x8 kf[4][2];
            const u16* kr0 = Kf0 + (long)(kvbase + m) * DD;
            #pragma unroll
            for (int mt = 0; mt < 4; ++mt)
                #pragma unroll
                for (int kst = 0; kst < 2; ++kst)
                    kf[mt][kst] = *(const s16x8*)(kr0 + mt * 16 * DD + kst * 32);
            s16x8 vf[2][4];
            const u16* vr0 = Vt0 + kvbase;
            #pragma unroll
            for (int kst = 0; kst < 2; ++kst)
                #pragma unroll
                for (int dt = 0; dt < 4; ++dt)
                    vf[kst][dt] = *(const s16x8*)(vr0 + (long)dt * 16 * SS + kst * 32);
            #pragma unroll
            for (int mt = 0; mt < 4; ++mt) {
                st[mt] = (f32x4){0.f, 0.f, 0.f, 0.f};
                #pragma unroll
                for (int kst = 0; kst < 2; ++kst)
                    st[mt] = __builtin_amdgcn_mfma_f32_16x16x32_bf16(kf[mt][kst], qf[kst], st[mt], 0, 0, 0);
            }
            if (tile == ntiles - 1) {
                #pragma unroll
                for (int mt = 0; mt < 4; ++mt)
                    #pragma unroll
                    for (int r = 0; r < 4; ++r) {
                        const int k_g = kvbase + mt * 16 + g * 4 + r;
                        if (k_g > q_g) st[mt][r] = -1e9f;
                    }
            }
            float tm = st[0][0];
            #pragma unroll
            for (int mt = 0; mt < 4; ++mt)
                #pragma unroll
                for (int r = 0; r < 4; ++r) tm = fmaxf(tm, st[mt][r]);
            tm = fmaxf(tm, __shfl_xor(tm, 16));
            tm = fmaxf(tm, __shfl_xor(tm, 32));
            const float mnew  = fmaxf(m_run, tm);
            const float alpha = exp2f(m_run - mnew);
            float rs = 0.f;
            #pragma unroll
            for (int mt = 0; mt < 4; ++mt)
                #pragma unroll
                for (int r = 0; r < 4; ++r) {
                    const float e = exp2f(st[mt][r] - mnew);
                    st[mt][r] = e;
                    rs += e;
                }
            rs += __shfl_xor(rs, 16);
            rs += __shfl_xor(rs, 32);
            l_run = l_run * alpha + rs;
            m_run = mnew;
            unsigned pk[4][2];
            #pragma unroll
            for (int mt = 0; mt < 4; ++mt) {
                pk[mt][0] = pack_bf16(st[mt][0], st[mt][1]);
                pk[mt][1] = pack_bf16(st[mt][2], st[mt][3]);
            }
            float av[4];
            #pragma unroll
            for (int r = 0; r < 4; ++r) av[r] = __shfl(alpha, 4 * g + r);
            #pragma unroll
            for (int dt = 0; dt < 4; ++dt)
                #pragma unroll
                for (int r = 0; r < 4; ++r) o[dt][r] *= av[r];
            #pragma unroll
            for (int kst = 0; kst < 2; ++kst) {
                frag_u pa;
                #pragma unroll
                for (int ww = 0; ww < 4; ++ww) {
                    const int srcl = m + 16 * (2 * (g & 1) + (ww >> 1));
                    const int v0 = __shfl((int)pk[2 * kst][ww & 1], srcl);
                    const int v1 = __shfl((int)pk[2 * kst + 1][ww & 1], srcl);
                    pa.u[ww] = (unsigned)((g & 2) ? v1 : v0);
                }
                #pragma unroll
                for (int dt = 0; dt < 4; ++dt)
                    o[dt] = __builtin_amdgcn_mfma_f32_16x16x32_bf16(pa.s, vf[kst][dt], o[dt], 0, 0, 0);
            }
        } else {
            #pragma unroll
            for (int mt = 0; mt < 4; ++mt) {
                st[mt] = (f32x4){0.f, 0.f, 0.f, 0.f};
                const float* kr = Kb0 + (long)(kvbase + mt * 16 + m) * DD + g * 8;
                #pragma unroll
                for (int kst = 0; kst < 2; ++kst) {
                    f32x4 x0 = *(const f32x4*)(kr + kst * 32);
                    f32x4 x1 = *(const f32x4*)(kr + kst * 32 + 4);
                    frag_u kf;
                    kf.u[0] = pack_bf16(x0[0], x0[1]);
                    kf.u[1] = pack_bf16(x0[2], x0[3]);
                    kf.u[2] = pack_bf16(x1[0], x1[1]);
                    kf.u[3] = pack_bf16(x1[2], x1[3]);
                    st[mt] = __builtin_amdgcn_mfma_f32_16x16x32_bf16(kf.s, qf[kst], st[mt], 0, 0, 0);
                }
            }
            if (tile == ntiles - 1) {
                #pragma unroll
                for (int mt = 0; mt < 4; ++mt)
                    #pragma unroll
                    for (int r = 0; r < 4; ++r) {
                        const int k_g = kvbase + mt * 16 + g * 4 + r;
                        if (k_g > q_g) st[mt][r] = -1e9f;
                    }
            }
            float tm = st[0][0];
            #pragma unroll
            for (int mt = 0; mt < 4; ++mt)
                #pragma unroll
                for (int r = 0; r < 4; ++r) tm = fmaxf(tm, st[mt][r]);
            tm = fmaxf(tm, __shfl_xor(tm, 16));
            tm = fmaxf(tm, __shfl_xor(tm, 32));
            const float mnew  = fmaxf(m_run, tm);
            const float alpha = exp2f(m_run - mnew);
            float rs = 0.f;
            #pragma unroll
            for (int mt = 0; mt < 4; ++mt)
                #pragma unroll
                for (int r = 0; r < 4; ++r) {
                    const float e = exp2f(st[mt][r] - mnew);
                    st[mt][r] = e;
                    rs += e;
                }
            rs += __shfl_xor(rs, 16);
            rs += __shfl_xor(rs, 32);
            l_run = l_run * alpha + rs;
            m_run = mnew;
            unsigned pk[4][2];
            #pragma unroll
            for (int mt = 0; mt < 4; ++mt) {
                pk[mt][0] = pack_bf16(st[mt][0], st[mt][1]);
                pk[mt][1] = pack_bf16(st[mt][2], st[mt][3]);
            }
            float av[4];
            #pragma unroll
            for (int r = 0; r < 4; ++r) av[r] = __shfl(alpha, 4 * g + r);
            #pragma unroll
            for (int dt = 0; dt < 4; ++dt)
                #pragma unroll
                for (int r = 0; r < 4; ++r) o[dt][r] *= av[r];
            #pragma unroll
            for (int kst = 0; kst < 2; ++kst) {
                frag_u pa;
                #pragma unroll
                for (int ww = 0; ww < 4; ++ww) {
                    const int srcl = m + 16 * (2 * (g & 1) + (ww >> 1));
                    const int v0 = __shfl((int)pk[2 * kst][ww & 1], srcl);
                    const int v1 = __shfl((int)pk[2 * kst + 1][ww & 1], srcl);
                    pa.u[ww] = (unsigned)((g & 2) ? v1 : v0);
                }
                const float* vcol = Vb0 + (long)(kvbase + kst * 32 + g * 8) * DD + m;
                #pragma unroll
                for (int dt = 0; dt < 4; ++dt) {
                    const float* vc = vcol + dt * 16;
                    frag_u vb;
                    #pragma unroll
                    for (int jj = 0; jj < 4; ++jj)
                        vb.u[jj] = pack_bf16(vc[(2 * jj) * DD], vc[(2 * jj + 1) * DD]);
                    o[dt] = __builtin_amdgcn_mfma_f32_16x16x32_bf16(pa.s, vb.s, o[dt], 0, 0, 0);
                }
            }
        }
    }

    for (int half = 4; half >= 1; half >>= 1) {
        if (w >= half && w < 2 * half) {
            const int slot = w - half;
            if (g == 0) { smM[slot][m] = m_run; smL[slot][m] = l_run; }
            #pragma unroll
            for (int dt = 0; dt < 4; ++dt)
                #pragma unroll
                for (int r = 0; r < 4; ++r)
                    mbuf[slot][(4 * g + r) * 68 + 16 * dt + m] = o[dt][r];
        }
        __syncthreads();
        if (w < half) {
            const float m2 = smM[w][m], l2 = smL[w][m];
            const float mn = fmaxf(m_run, m2);
            const float a1 = exp2f(m_run - mn);
            const float a2 = exp2f(m2 - mn);
            l_run = l_run * a1 + l2 * a2;
            m_run = mn;
            float av1[4], av2[4];
            #pragma unroll
            for (int r = 0; r < 4; ++r) {
                av1[r] = __shfl(a1, 4 * g + r);
                av2[r] = __shfl(a2, 4 * g + r);
            }
            #pragma unroll
            for (int dt = 0; dt < 4; ++dt)
                #pragma unroll
                for (int r = 0; r < 4; ++r)
                    o[dt][r] = o[dt][r] * av1[r] +
                               mbuf[w][(4 * g + r) * 68 + 16 * dt + m] * av2[r];
        }
        __syncthreads();
    }

    if (w == 0) {
        float lv[4];
        #pragma unroll
        for (int r = 0; r < 4; ++r) lv[r] = 1.0f / __shfl(l_run, 4 * g + r);
        float* Ob = O + ((long)b * SS + q0) * DD;
        #pragma unroll
        for (int dt = 0; dt < 4; ++dt)
            #pragma unroll
            for (int r = 0; r < 4; ++r)
                Ob[(4 * g + r) * DD + dt * 16 + m] = o[dt][r] * lv[r];
    }
}

extern "C" void kernel_launch(void* const* d_in, const int* in_sizes, int n_in,
                              void* d_out, int out_size, void* d_ws, size_t ws_size,
                              hipStream_t stream) {
    const float* Q = (const float*)d_in[0];
    const float* K = (const float*)d_in[1];
    const float* V = (const float*)d_in[2];
    float* O = (float*)d_out;
    const size_t tensor_b = (size_t)BB * SS * DD * sizeof(u16);        // 2 MiB
    const size_t part_b   = (size_t)4096 * SLOT_F * sizeof(float);     // ~16.5 MiB
    if (ws_size >= 2 * tensor_b + part_b) {
        u16* Kbf = (u16*)d_ws;
        u16* VT  = (u16*)((char*)d_ws + tensor_b);
        float* part = (float*)((char*)d_ws + 2 * tensor_b);
        conv_k   <<<dim3(BB * SS * DD / 8 / 256), dim3(256), 0, stream>>>(K, Kbf);
        conv_vt  <<<dim3(BB * (SS / 64)),         dim3(256), 0, stream>>>(V, VT);
        attn_part<<<dim3(4096),                   dim3(512), 0, stream>>>(Q, Kbf, VT, part);
        attn_merge<<<dim3(BB * (SS / 16)),        dim3(256), 0, stream>>>(part, O);
    } else if (ws_size >= 2 * tensor_b) {
        u16* Kbf = (u16*)d_ws;
        u16* VT  = (u16*)((char*)d_ws + tensor_b);
        conv_k <<<dim3(BB * SS * DD / 8 / 256), dim3(256), 0, stream>>>(K, Kbf);
        conv_vt<<<dim3(BB * (SS / 64)),        dim3(256), 0, stream>>>(V, VT);
        attn_fwd<true><<<dim3(BB * (SS / 16)), dim3(512), 0, stream>>>(Q, K, V, O, Kbf, VT);
    } else {
        attn_fwd<false><<<dim3(BB * (SS / 16)), dim3(512), 0, stream>>>(Q, K, V, O, nullptr, nullptr);
    }
}

// Round 7
// 73.331 us; speedup vs baseline: 1.3156x; 1.3156x over previous
//
#include <hip/hip_runtime.h>

#define BB 4
#define SS 4096
#define DD 64
// scale = 1/sqrt(4096), with log2(e) folded in so softmax runs in exp2 domain
#define QSCALE (0.015625f * 1.44269504088896f)

typedef __attribute__((ext_vector_type(4)))  float f32x4;
typedef __attribute__((ext_vector_type(16))) float f32x16;
typedef __attribute__((ext_vector_type(8)))  short s16x8;
typedef unsigned short u16;

union frag_u { unsigned u[4]; s16x8 s; };

#define SLOT_F 2112   // 32x64 o (2048) + m (32 @2048) + l (32 @2080)

// Round-half-up pack of two f32 into (lo,hi) bf16 pair.
__device__ __forceinline__ unsigned pack_bf16(float lo, float hi) {
    union { float f; unsigned u; } a, b; a.f = lo; b.f = hi;
    return __builtin_amdgcn_perm(b.u + 0x8000u, a.u + 0x8000u, 0x07060302u);
}

// Swap: lanes 0-31 keep a, get partner(l+32)'s a in b; lanes 32-63 get
// partner(l-32)'s b in a, keep b in b.
__device__ __forceinline__ void pl32swap(unsigned &a, unsigned &b) {
    asm volatile("v_permlane32_swap_b32 %0, %1" : "+v"(a), "+v"(b));
}

// ---- prep 1: K (fp32 row-major) -> Kbf (bf16 row-major) ----
__global__ __launch_bounds__(256) void conv_k(const float* __restrict__ K,
                                              u16* __restrict__ Kbf) {
    const long i = ((long)blockIdx.x * 256 + threadIdx.x) * 8;
    f32x4 a = *(const f32x4*)(K + i);
    f32x4 b = *(const f32x4*)(K + i + 4);
    frag_u f;
    f.u[0] = pack_bf16(a[0], a[1]);
    f.u[1] = pack_bf16(a[2], a[3]);
    f.u[2] = pack_bf16(b[0], b[1]);
    f.u[3] = pack_bf16(b[2], b[3]);
    *(s16x8*)(Kbf + i) = f.s;
}

// ---- prep 2: V (fp32 [b][s][d]) -> VT (bf16 [b][d][s]) ----
__global__ __launch_bounds__(256) void conv_vt(const float* __restrict__ V,
                                               u16* __restrict__ VT) {
    __shared__ u16 tile[64][72];
    const int b  = blockIdx.x >> 6;
    const int kt = blockIdx.x & 63;
    const int tid = threadIdx.x;
    const float* Vb = V + ((long)b * SS + kt * 64) * DD;
    {
        const int kk = tid >> 4;
        const int d4 = (tid & 15) * 4;
        #pragma unroll
        for (int p = 0; p < 4; ++p) {
            const int k = kk + p * 16;
            f32x4 v = *(const f32x4*)(Vb + k * DD + d4);
            #pragma unroll
            for (int c = 0; c < 4; ++c) {
                union { float f; unsigned u; } x; x.f = v[c];
                tile[d4 + c][k] = (u16)((x.u + 0x8000u) >> 16);
            }
        }
    }
    __syncthreads();
    {
        const int d  = tid >> 2;
        const int kg = (tid & 3) * 16;
        u16* dst = VT + ((long)b * DD + d) * SS + kt * 64 + kg;
        frag_u w0, w1;
        #pragma unroll
        for (int j = 0; j < 4; ++j) {
            w0.u[j] = (unsigned)tile[d][kg + 2 * j] | ((unsigned)tile[d][kg + 2 * j + 1] << 16);
            w1.u[j] = (unsigned)tile[d][kg + 8 + 2 * j] | ((unsigned)tile[d][kg + 9 + 2 * j] << 16);
        }
        *(s16x8*)dst = w0.s;
        *(s16x8*)(dst + 8) = w1.s;
    }
}

// ============ Phase 1: independent waves, 32 q-rows, CH tiles/wave ==========
// Wave W = blockIdx*4 + (tid>>6): b = W&3, t = (W>>2)&127, c = W>>9.
// Strip t covers q [t*32, t*32+32); ntiles = (t>>1)+1; nch = (t>>S1)+1.
template<int S1>
__global__ __launch_bounds__(256, 3) void
attn_part32(const float* __restrict__ Q, const u16* __restrict__ Kbf,
            const u16* __restrict__ VT, float* __restrict__ part)
{
    constexpr int CH = 1 << (S1 - 1);
    const int W = blockIdx.x * 4 + (threadIdx.x >> 6);
    const int b = W & 3;
    const int t = (W >> 2) & 127;
    const int c = W >> 9;
    const int ntiles = (t >> 1) + 1;
    const int nch = (t >> S1) + 1;
    if (c >= nch) return;   // block-uniform (t,c shared by all 4 waves? no — W differs per wave, but exit is wave-uniform; no barriers/LDS anywhere)

    const int lane = threadIdx.x & 63;
    const int ql  = lane & 31;
    const int hi  = lane >> 5;
    const int hi8 = hi * 8;
    const int q0  = t * 32;
    const int q_g = q0 + ql;

    const u16* Kb = Kbf + (long)b * SS * DD;
    const u16* Vb = VT  + (long)b * DD * SS;

    // ---- Q B-frags: B[d = kst*16 + hi*8 + j][q = ql], scale folded ----
    s16x8 qf[4];
    {
        const float* qrow = Q + ((long)b * SS + q_g) * DD + hi8;
        #pragma unroll
        for (int kst = 0; kst < 4; ++kst) {
            f32x4 x0 = *(const f32x4*)(qrow + kst * 16);
            f32x4 x1 = *(const f32x4*)(qrow + kst * 16 + 4);
            frag_u f;
            f.u[0] = pack_bf16(x0[0] * QSCALE, x0[1] * QSCALE);
            f.u[1] = pack_bf16(x0[2] * QSCALE, x0[3] * QSCALE);
            f.u[2] = pack_bf16(x1[0] * QSCALE, x1[1] * QSCALE);
            f.u[3] = pack_bf16(x1[2] * QSCALE, x1[3] * QSCALE);
            qf[kst] = f.s;
        }
    }

    f32x16 o0, o1;
    #pragma unroll
    for (int r = 0; r < 16; ++r) { o0[r] = 0.f; o1[r] = 0.f; }
    float m_run = -1e30f, l_run = 0.f;

    const int tlo = c * CH;
    const int thi = min(ntiles, tlo + CH);

    for (int tile = tlo; tile < thi; ++tile) {
        const int kvb = tile * 64;

        // ---- batch all K and V fragment loads (16 x 16B) ----
        s16x8 kf[2][4];
        #pragma unroll
        for (int kt = 0; kt < 2; ++kt) {
            const u16* kr = Kb + (long)(kvb + kt * 32 + ql) * DD + hi8;
            #pragma unroll
            for (int kst = 0; kst < 4; ++kst)
                kf[kt][kst] = *(const s16x8*)(kr + kst * 16);
        }
        s16x8 vf[2][4];
        #pragma unroll
        for (int dt = 0; dt < 2; ++dt) {
            const u16* vr = Vb + (long)(dt * 32 + ql) * SS + kvb + hi8;
            #pragma unroll
            for (int ks = 0; ks < 4; ++ks)
                vf[dt][ks] = *(const s16x8*)(vr + ks * 16);
        }

        // ---- S^T = K · Q^T : col=q(=ql), row=k = kt*32 + (r&3)+8*(r>>2)+4*hi
        f32x16 st0, st1;
        #pragma unroll
        for (int r = 0; r < 16; ++r) { st0[r] = 0.f; st1[r] = 0.f; }
        #pragma unroll
        for (int kst = 0; kst < 4; ++kst) {
            st0 = __builtin_amdgcn_mfma_f32_32x32x16_bf16(kf[0][kst], qf[kst], st0, 0, 0, 0);
            st1 = __builtin_amdgcn_mfma_f32_32x32x16_bf16(kf[1][kst], qf[kst], st1, 0, 0, 0);
        }

        // ---- causal mask (global last tile only) ----
        if (tile == ntiles - 1) {
            #pragma unroll
            for (int r = 0; r < 16; ++r) {
                const int crow = (r & 3) + 8 * (r >> 2) + 4 * hi;
                if (kvb + crow > q_g)      st0[r] = -1e9f;
                if (kvb + 32 + crow > q_g) st1[r] = -1e9f;
            }
        }

        // ---- online softmax: lane owns row q_g; halves combine via 1 shfl ----
        float tm = -1e30f;
        #pragma unroll
        for (int r = 0; r < 16; ++r) { tm = fmaxf(tm, st0[r]); tm = fmaxf(tm, st1[r]); }
        tm = fmaxf(tm, __shfl_xor(tm, 32));
        const float mnew  = fmaxf(m_run, tm);
        const float alpha = exp2f(m_run - mnew);
        float rs = 0.f;
        #pragma unroll
        for (int r = 0; r < 16; ++r) {
            st0[r] = exp2f(st0[r] - mnew); rs += st0[r];
            st1[r] = exp2f(st1[r] - mnew); rs += st1[r];
        }
        rs += __shfl_xor(rs, 32);
        l_run = l_run * alpha + rs;
        m_run = mnew;

        // ---- P -> bf16 B-frags via permlane32_swap (k packing matches V^T) --
        frag_u pf[4];
        #pragma unroll
        for (int kt = 0; kt < 2; ++kt) {
            unsigned w[8];
            #pragma unroll
            for (int j = 0; j < 8; ++j)
                w[j] = kt == 0 ? pack_bf16(st0[2 * j], st0[2 * j + 1])
                               : pack_bf16(st1[2 * j], st1[2 * j + 1]);
            unsigned a0 = w[0], b0 = w[2]; pl32swap(a0, b0);
            unsigned a1 = w[1], b1 = w[3]; pl32swap(a1, b1);
            pf[2 * kt].u[0] = a0; pf[2 * kt].u[1] = a1;
            pf[2 * kt].u[2] = b0; pf[2 * kt].u[3] = b1;
            unsigned a2 = w[4], b2 = w[6]; pl32swap(a2, b2);
            unsigned a3 = w[5], b3 = w[7]; pl32swap(a3, b3);
            pf[2 * kt + 1].u[0] = a2; pf[2 * kt + 1].u[1] = a3;
            pf[2 * kt + 1].u[2] = b2; pf[2 * kt + 1].u[3] = b3;
        }

        // ---- rescale O^T (col=q -> lane-local alpha, no shuffles) ----
        #pragma unroll
        for (int r = 0; r < 16; ++r) { o0[r] *= alpha; o1[r] *= alpha; }

        // ---- O^T += V^T · P^T ----
        #pragma unroll
        for (int ks = 0; ks < 4; ++ks) {
            o0 = __builtin_amdgcn_mfma_f32_32x32x16_bf16(vf[0][ks], pf[ks].s, o0, 0, 0, 0);
            o1 = __builtin_amdgcn_mfma_f32_32x32x16_bf16(vf[1][ks], pf[ks].s, o1, 0, 0, 0);
        }
    }

    // ---- write unnormalized partial: [q][d] f32 + m + l ----
    {
        const int a = t >> S1, rem = t & ((1 << S1) - 1);
        const long base = (long)t + (long)CH * a * (a - 1) + (long)a * rem;
        float* P = part + ((base + c) * 4 + b) * SLOT_F;
        #pragma unroll
        for (int dt = 0; dt < 2; ++dt)
            #pragma unroll
            for (int rg = 0; rg < 4; ++rg) {
                f32x4 v;
                #pragma unroll
                for (int rr = 0; rr < 4; ++rr)
                    v[rr] = dt == 0 ? o0[4 * rg + rr] : o1[4 * rg + rr];
                *(f32x4*)(P + ql * 64 + dt * 32 + rg * 8 + hi * 4) = v;
            }
        if (hi == 0) { P[2048 + ql] = m_run; P[2080 + ql] = l_run; }
    }
}

// ============ Phase 2: merge nch partials per strip, normalize ==============
template<int S1>
__global__ __launch_bounds__(256) void
attn_merge32(const float* __restrict__ part, float* __restrict__ O)
{
    constexpr int CH = 1 << (S1 - 1);
    const int b = blockIdx.x & 3;
    const int t = blockIdx.x >> 2;
    const int nch = (t >> S1) + 1;
    const int a = t >> S1, rem = t & ((1 << S1) - 1);
    const long base = (long)t + (long)CH * a * (a - 1) + (long)a * rem;
    const int q  = threadIdx.x >> 3;
    const int d8 = (threadIdx.x & 7) * 8;

    float mstar = -1e30f;
    for (int c = 0; c < nch; ++c)
        mstar = fmaxf(mstar, part[((base + c) * 4 + b) * SLOT_F + 2048 + q]);

    f32x4 acc0 = (f32x4){0.f, 0.f, 0.f, 0.f};
    f32x4 acc1 = (f32x4){0.f, 0.f, 0.f, 0.f};
    float ls = 0.f;
    for (int c = 0; c < nch; ++c) {
        const float* P = part + ((base + c) * 4 + b) * SLOT_F;
        const float wgt = exp2f(P[2048 + q] - mstar);
        ls += wgt * P[2080 + q];
        acc0 += wgt * *(const f32x4*)(P + q * 64 + d8);
        acc1 += wgt * *(const f32x4*)(P + q * 64 + d8 + 4);
    }
    const float inv = 1.0f / ls;
    float* Ob = O + ((long)b * SS + t * 32 + q) * DD + d8;
    *(f32x4*)Ob       = acc0 * inv;
    *(f32x4*)(Ob + 4) = acc1 * inv;
}

// ============ Last-resort fallback (round-3 kernel, no workspace) ===========
__global__ __launch_bounds__(512, 4) void
attn_fb(const float* __restrict__ Q, const float* __restrict__ K,
        const float* __restrict__ V, float* __restrict__ O)
{
    __shared__ float mbuf[4][16 * 68];
    __shared__ float smM[4][16];
    __shared__ float smL[4][16];
    const int tid = threadIdx.x, w = tid >> 6, lane = tid & 63;
    const int m = lane & 15, g = lane >> 4;
    const int idx = blockIdx.x, t = 255 - (idx >> 2), b = idx & 3, q0 = t * 16;
    const float* Kb0 = K + (long)b * SS * DD;
    const float* Vb0 = V + (long)b * SS * DD;
    typedef __attribute__((ext_vector_type(4))) float f4;
    s16x8 qf[2];
    {
        const float* qrow = Q + ((long)b * SS + q0 + m) * DD + g * 8;
        #pragma unroll
        for (int kst = 0; kst < 2; ++kst) {
            f4 x0 = *(const f4*)(qrow + kst * 32);
            f4 x1 = *(const f4*)(qrow + kst * 32 + 4);
            frag_u f;
            f.u[0] = pack_bf16(x0[0] * QSCALE, x0[1] * QSCALE);
            f.u[1] = pack_bf16(x0[2] * QSCALE, x0[3] * QSCALE);
            f.u[2] = pack_bf16(x1[0] * QSCALE, x1[1] * QSCALE);
            f.u[3] = pack_bf16(x1[2] * QSCALE, x1[3] * QSCALE);
            qf[kst] = f.s;
        }
    }
    f4 o[4];
    #pragma unroll
    for (int dt = 0; dt < 4; ++dt) o[dt] = (f4){0.f, 0.f, 0.f, 0.f};
    float m_run = -1e30f, l_run = 0.f;
    const int ntiles = (q0 >> 6) + 1, q_g = q0 + m;
    for (int tile = w; tile < ntiles; tile += 8) {
        const int kvbase = tile * 64;
        f4 st[4];
        #pragma unroll
        for (int mt = 0; mt < 4; ++mt) {
            st[mt] = (f4){0.f, 0.f, 0.f, 0.f};
            const float* kr = Kb0 + (long)(kvbase + mt * 16 + m) * DD + g * 8;
            #pragma unroll
            for (int kst = 0; kst < 2; ++kst) {
                f4 x0 = *(const f4*)(kr + kst * 32);
                f4 x1 = *(const f4*)(kr + kst * 32 + 4);
                frag_u kf;
                kf.u[0] = pack_bf16(x0[0], x0[1]);
                kf.u[1] = pack_bf16(x0[2], x0[3]);
                kf.u[2] = pack_bf16(x1[0], x1[1]);
                kf.u[3] = pack_bf16(x1[2], x1[3]);
                st[mt] = __builtin_amdgcn_mfma_f32_16x16x32_bf16(kf.s, qf[kst], st[mt], 0, 0, 0);
            }
        }
        if (tile == ntiles - 1) {
            #pragma unroll
            for (int mt = 0; mt < 4; ++mt)
                #pragma unroll
                for (int r = 0; r < 4; ++r)
                    if (kvbase + mt * 16 + g * 4 + r > q_g) st[mt][r] = -1e9f;
        }
        float tm = st[0][0];
        #pragma unroll
        for (int mt = 0; mt < 4; ++mt)
            #pragma unroll
            for (int r = 0; r < 4; ++r) tm = fmaxf(tm, st[mt][r]);
        tm = fmaxf(tm, __shfl_xor(tm, 16));
        tm = fmaxf(tm, __shfl_xor(tm, 32));
        const float mnew = fmaxf(m_run, tm);
        const float alpha = exp2f(m_run - mnew);
        float rs = 0.f;
        #pragma unroll
        for (int mt = 0; mt < 4; ++mt)
            #pragma unroll
            for (int r = 0; r < 4; ++r) {
                const float e = exp2f(st[mt][r] - mnew);
                st[mt][r] = e; rs += e;
            }
        rs += __shfl_xor(rs, 16);
        rs += __shfl_xor(rs, 32);
        l_run = l_run * alpha + rs; m_run = mnew;
        unsigned pk[4][2];
        #pragma unroll
        for (int mt = 0; mt < 4; ++mt) {
            pk[mt][0] = pack_bf16(st[mt][0], st[mt][1]);
            pk[mt][1] = pack_bf16(st[mt][2], st[mt][3]);
        }
        float av[4];
        #pragma unroll
        for (int r = 0; r < 4; ++r) av[r] = __shfl(alpha, 4 * g + r);
        #pragma unroll
        for (int dt = 0; dt < 4; ++dt)
            #pragma unroll
            for (int r = 0; r < 4; ++r) o[dt][r] *= av[r];
        #pragma unroll
        for (int kst = 0; kst < 2; ++kst) {
            frag_u pa;
            #pragma unroll
            for (int ww = 0; ww < 4; ++ww) {
                const int srcl = m + 16 * (2 * (g & 1) + (ww >> 1));
                const int v0 = __shfl((int)pk[2 * kst][ww & 1], srcl);
                const int v1 = __shfl((int)pk[2 * kst + 1][ww & 1], srcl);
                pa.u[ww] = (unsigned)((g & 2) ? v1 : v0);
            }
            const float* vcol = Vb0 + (long)(kvbase + kst * 32 + g * 8) * DD + m;
            #pragma unroll
            for (int dt = 0; dt < 4; ++dt) {
                const float* vc = vcol + dt * 16;
                frag_u vb;
                #pragma unroll
                for (int jj = 0; jj < 4; ++jj)
                    vb.u[jj] = pack_bf16(vc[(2 * jj) * DD], vc[(2 * jj + 1) * DD]);
                o[dt] = __builtin_amdgcn_mfma_f32_16x16x32_bf16(pa.s, vb.s, o[dt], 0, 0, 0);
            }
        }
    }
    for (int half = 4; half >= 1; half >>= 1) {
        if (w >= half && w < 2 * half) {
            const int slot = w - half;
            if (g == 0) { smM[slot][m] = m_run; smL[slot][m] = l_run; }
            #pragma unroll
            for (int dt = 0; dt < 4; ++dt)
                #pragma unroll
                for (int r = 0; r < 4; ++r)
                    mbuf[slot][(4 * g + r) * 68 + 16 * dt + m] = o[dt][r];
        }
        __syncthreads();
        if (w < half) {
            const float m2 = smM[w][m], l2 = smL[w][m];
            const float mn = fmaxf(m_run, m2);
            const float a1 = exp2f(m_run - mn), a2 = exp2f(m2 - mn);
            l_run = l_run * a1 + l2 * a2; m_run = mn;
            float av1[4], av2[4];
            #pragma unroll
            for (int r = 0; r < 4; ++r) {
                av1[r] = __shfl(a1, 4 * g + r);
                av2[r] = __shfl(a2, 4 * g + r);
            }
            #pragma unroll
            for (int dt = 0; dt < 4; ++dt)
                #pragma unroll
                for (int r = 0; r < 4; ++r)
                    o[dt][r] = o[dt][r] * av1[r] +
                               mbuf[w][(4 * g + r) * 68 + 16 * dt + m] * av2[r];
        }
        __syncthreads();
    }
    if (w == 0) {
        float lv[4];
        #pragma unroll
        for (int r = 0; r < 4; ++r) lv[r] = 1.0f / __shfl(l_run, 4 * g + r);
        float* Ob = O + ((long)b * SS + q0) * DD;
        #pragma unroll
        for (int dt = 0; dt < 4; ++dt)
            #pragma unroll
            for (int r = 0; r < 4; ++r)
                Ob[(4 * g + r) * DD + dt * 16 + m] = o[dt][r] * lv[r];
    }
}

extern "C" void kernel_launch(void* const* d_in, const int* in_sizes, int n_in,
                              void* d_out, int out_size, void* d_ws, size_t ws_size,
                              hipStream_t stream) {
    const float* Q = (const float*)d_in[0];
    const float* K = (const float*)d_in[1];
    const float* V = (const float*)d_in[2];
    float* O = (float*)d_out;

    const size_t tensor_b = (size_t)BB * SS * DD * sizeof(u16);   // 2 MiB each
    const size_t conv_b   = 2 * tensor_b;
    const size_t s4_b  = (size_t)4352 * SLOT_F * sizeof(float);   // 36.8 MB
    const size_t s8_b  = (size_t)2304 * SLOT_F * sizeof(float);   // 19.5 MB
    const size_t s16_b = (size_t)1280 * SLOT_F * sizeof(float);   // 10.8 MB

    if (ws_size >= conv_b + s16_b) {
        u16* Kbf = (u16*)d_ws;
        u16* VT  = (u16*)((char*)d_ws + tensor_b);
        float* part = (float*)((char*)d_ws + conv_b);
        conv_k <<<dim3(BB * SS * DD / 8 / 256), dim3(256), 0, stream>>>(K, Kbf);
        conv_vt<<<dim3(BB * (SS / 64)),         dim3(256), 0, stream>>>(V, VT);
        if (ws_size >= conv_b + s4_b) {
            attn_part32<3><<<dim3(128 * 16), dim3(256), 0, stream>>>(Q, Kbf, VT, part);
            attn_merge32<3><<<dim3(512), dim3(256), 0, stream>>>(part, O);
        } else if (ws_size >= conv_b + s8_b) {
            attn_part32<4><<<dim3(128 * 8), dim3(256), 0, stream>>>(Q, Kbf, VT, part);
            attn_merge32<4><<<dim3(512), dim3(256), 0, stream>>>(part, O);
        } else {
            attn_part32<5><<<dim3(128 * 4), dim3(256), 0, stream>>>(Q, Kbf, VT, part);
            attn_merge32<5><<<dim3(512), dim3(256), 0, stream>>>(part, O);
        }
    } else {
        attn_fb<<<dim3(BB * (SS / 16)), dim3(512), 0, stream>>>(Q, K, V, O);
    }
}

// Round 8
// 51.753 us; speedup vs baseline: 1.8641x; 1.4169x over previous
//
#include <hip/hip_runtime.h>

#define BB 4
#define SS 4096
#define DD 64
// scale = 1/sqrt(4096), with log2(e) folded in so softmax runs in exp2 domain
#define QSCALE (0.015625f * 1.44269504088896f)

typedef __attribute__((ext_vector_type(4)))  float f32x4;
typedef __attribute__((ext_vector_type(16))) float f32x16;
typedef __attribute__((ext_vector_type(8)))  short s16x8;
typedef unsigned short u16;

union frag_u { unsigned u[4]; s16x8 s; };

#define SLOT_F 2112   // 8 chunks x 64 lanes x 4 f32 (2048) + m[32] + l[32]

// Round-half-up pack of two f32 into (lo,hi) bf16 pair.
__device__ __forceinline__ unsigned pack_bf16(float lo, float hi) {
    union { float f; unsigned u; } a, b; a.f = lo; b.f = hi;
    return __builtin_amdgcn_perm(b.u + 0x8000u, a.u + 0x8000u, 0x07060302u);
}

__device__ __forceinline__ void pl32swap(unsigned &a, unsigned &b) {
    asm volatile("v_permlane32_swap_b32 %0, %1" : "+v"(a), "+v"(b));
}

// ---- prep 1: K -> fragment-major Kf[b][tile][kt][kst][lane] (8 bf16 each) --
// entry g: lane=g&63, kst=(g>>6)&3, kt=(g>>8)&1, tile=(g>>9)&63, b=g>>15
__global__ __launch_bounds__(256) void conv_kf(const float* __restrict__ K,
                                               u16* __restrict__ Kf) {
    const int g    = blockIdx.x * 256 + threadIdx.x;
    const int lane = g & 63, kst = (g >> 6) & 3, kt = (g >> 8) & 1;
    const int tile = (g >> 9) & 63, b = g >> 15;
    const int ql = lane & 31, hi = lane >> 5;
    const long src = ((long)b * SS + tile * 64 + kt * 32 + ql) * DD + kst * 16 + hi * 8;
    f32x4 x0 = *(const f32x4*)(K + src);
    f32x4 x1 = *(const f32x4*)(K + src + 4);
    frag_u f;
    f.u[0] = pack_bf16(x0[0], x0[1]);
    f.u[1] = pack_bf16(x0[2], x0[3]);
    f.u[2] = pack_bf16(x1[0], x1[1]);
    f.u[3] = pack_bf16(x1[2], x1[3]);
    *(s16x8*)(Kf + (long)g * 8) = f.s;   // coalesced 1KB per wave
}

// ---- prep 2: V -> fragment-major Vf[b][tile][dt][ks][lane] (transposed) ----
__global__ __launch_bounds__(256) void conv_vf(const float* __restrict__ V,
                                               u16* __restrict__ Vf) {
    __shared__ u16 tl[64][72];           // [d][s_local]
    const int b = blockIdx.x >> 6;
    const int tile = blockIdx.x & 63;
    const int tid = threadIdx.x;
    const float* Vb = V + ((long)b * SS + tile * 64) * DD;
    {
        const int kk = tid >> 4;
        const int d4 = (tid & 15) * 4;
        #pragma unroll
        for (int p = 0; p < 4; ++p) {
            const int k = kk + p * 16;
            f32x4 v = *(const f32x4*)(Vb + k * DD + d4);
            #pragma unroll
            for (int c = 0; c < 4; ++c) {
                union { float f; unsigned u; } x; x.f = v[c];
                tl[d4 + c][k] = (u16)((x.u + 0x8000u) >> 16);
            }
        }
    }
    __syncthreads();
    {
        const int ks = tid >> 6, lane = tid & 63;
        const int ql = lane & 31, hi = lane >> 5;
        const int s0 = ks * 16 + hi * 8;
        u16* out = Vf + (((long)(b * 64 + tile) * 2) * 4 + ks) * 64 * 8 + lane * 8;
        #pragma unroll
        for (int dt = 0; dt < 2; ++dt) {
            const int row = dt * 32 + ql;
            frag_u f;
            #pragma unroll
            for (int j = 0; j < 4; ++j)
                f.u[j] = (unsigned)tl[row][s0 + 2 * j] |
                         ((unsigned)tl[row][s0 + 2 * j + 1] << 16);
            *(s16x8*)(out + (long)dt * 4 * 64 * 8) = f.s;
        }
    }
}

// ============ Phase 1: independent waves, 32 q-rows, 4 tiles/wave ===========
#define S1 3
#define CHT 4
__global__ __launch_bounds__(256, 3) void
attn_part32(const float* __restrict__ Q, const u16* __restrict__ Kf,
            const u16* __restrict__ Vf, float* __restrict__ part)
{
    const int W = blockIdx.x * 4 + (threadIdx.x >> 6);
    const int b = W & 3;
    const int t = (W >> 2) & 127;
    const int c = W >> 9;
    const int ntiles = (t >> 1) + 1;
    const int nch = (t >> S1) + 1;
    if (c >= nch) return;                 // wave-uniform; no barriers/LDS here

    const int lane = threadIdx.x & 63;
    const int ql = lane & 31, hi = lane >> 5, hi8 = hi * 8;
    const int q0 = t * 32;
    const int q_g = q0 + ql;

    // ---- Q B-frags: B[d = kst*16 + hi*8 + j][q = ql], scale folded ----
    s16x8 qf[4];
    {
        const float* qrow = Q + ((long)b * SS + q_g) * DD + hi8;
        #pragma unroll
        for (int kst = 0; kst < 4; ++kst) {
            f32x4 x0 = *(const f32x4*)(qrow + kst * 16);
            f32x4 x1 = *(const f32x4*)(qrow + kst * 16 + 4);
            frag_u f;
            f.u[0] = pack_bf16(x0[0] * QSCALE, x0[1] * QSCALE);
            f.u[1] = pack_bf16(x0[2] * QSCALE, x0[3] * QSCALE);
            f.u[2] = pack_bf16(x1[0] * QSCALE, x1[1] * QSCALE);
            f.u[3] = pack_bf16(x1[2] * QSCALE, x1[3] * QSCALE);
            qf[kst] = f.s;
        }
    }

    f32x16 o0, o1;
    #pragma unroll
    for (int r = 0; r < 16; ++r) { o0[r] = 0.f; o1[r] = 0.f; }
    float m_run = -1e30f, l_run = 0.f;

    const int tlo = c * CHT;
    const int thi = min(ntiles, tlo + CHT);

    for (int tile = tlo; tile < thi; ++tile) {
        // ---- fully-coalesced fragment loads (1KB per instruction) ----
        const u16* Kt = Kf + (long)((b * 64 + tile) * 4096) + lane * 8;
        const u16* Vt = Vf + (long)((b * 64 + tile) * 4096) + lane * 8;
        s16x8 kf[2][4], vf[2][4];
        #pragma unroll
        for (int kt = 0; kt < 2; ++kt)
            #pragma unroll
            for (int kst = 0; kst < 4; ++kst)
                kf[kt][kst] = *(const s16x8*)(Kt + (kt * 4 + kst) * 512);
        #pragma unroll
        for (int dt = 0; dt < 2; ++dt)
            #pragma unroll
            for (int ks = 0; ks < 4; ++ks)
                vf[dt][ks] = *(const s16x8*)(Vt + (dt * 4 + ks) * 512);

        // ---- S^T = K · Q^T : col=q(=ql), row=k = kt*32 + (r&3)+8*(r>>2)+4*hi
        f32x16 st0, st1;
        #pragma unroll
        for (int r = 0; r < 16; ++r) { st0[r] = 0.f; st1[r] = 0.f; }
        #pragma unroll
        for (int kst = 0; kst < 4; ++kst) {
            st0 = __builtin_amdgcn_mfma_f32_32x32x16_bf16(kf[0][kst], qf[kst], st0, 0, 0, 0);
            st1 = __builtin_amdgcn_mfma_f32_32x32x16_bf16(kf[1][kst], qf[kst], st1, 0, 0, 0);
        }

        const int kvb = tile * 64;
        if (tile == ntiles - 1) {
            #pragma unroll
            for (int r = 0; r < 16; ++r) {
                const int crow = (r & 3) + 8 * (r >> 2) + 4 * hi;
                if (kvb + crow > q_g)      st0[r] = -1e9f;
                if (kvb + 32 + crow > q_g) st1[r] = -1e9f;
            }
        }

        // ---- online softmax: lane owns row q_g; 1 cross-lane shfl ----
        float tm = -1e30f;
        #pragma unroll
        for (int r = 0; r < 16; ++r) { tm = fmaxf(tm, st0[r]); tm = fmaxf(tm, st1[r]); }
        tm = fmaxf(tm, __shfl_xor(tm, 32));
        const float mnew  = fmaxf(m_run, tm);
        const float alpha = exp2f(m_run - mnew);
        float rs = 0.f;
        #pragma unroll
        for (int r = 0; r < 16; ++r) {
            st0[r] = exp2f(st0[r] - mnew); rs += st0[r];
            st1[r] = exp2f(st1[r] - mnew); rs += st1[r];
        }
        rs += __shfl_xor(rs, 32);
        l_run = l_run * alpha + rs;
        m_run = mnew;

        // ---- P -> bf16 B-frags via permlane32_swap ----
        frag_u pf[4];
        #pragma unroll
        for (int kt = 0; kt < 2; ++kt) {
            unsigned w[8];
            #pragma unroll
            for (int j = 0; j < 8; ++j)
                w[j] = kt == 0 ? pack_bf16(st0[2 * j], st0[2 * j + 1])
                               : pack_bf16(st1[2 * j], st1[2 * j + 1]);
            unsigned a0 = w[0], b0 = w[2]; pl32swap(a0, b0);
            unsigned a1 = w[1], b1 = w[3]; pl32swap(a1, b1);
            pf[2 * kt].u[0] = a0; pf[2 * kt].u[1] = a1;
            pf[2 * kt].u[2] = b0; pf[2 * kt].u[3] = b1;
            unsigned a2 = w[4], b2 = w[6]; pl32swap(a2, b2);
            unsigned a3 = w[5], b3 = w[7]; pl32swap(a3, b3);
            pf[2 * kt + 1].u[0] = a2; pf[2 * kt + 1].u[1] = a3;
            pf[2 * kt + 1].u[2] = b2; pf[2 * kt + 1].u[3] = b3;
        }

        // ---- rescale O^T (col=q -> lane-local alpha) ----
        #pragma unroll
        for (int r = 0; r < 16; ++r) { o0[r] *= alpha; o1[r] *= alpha; }

        // ---- O^T += V^T · P^T ----
        #pragma unroll
        for (int ks = 0; ks < 4; ++ks) {
            o0 = __builtin_amdgcn_mfma_f32_32x32x16_bf16(vf[0][ks], pf[ks].s, o0, 0, 0, 0);
            o1 = __builtin_amdgcn_mfma_f32_32x32x16_bf16(vf[1][ks], pf[ks].s, o1, 0, 0, 0);
        }
    }

    // ---- write partial, accumulator-lane order (fully coalesced) ----
    {
        const int a = t >> S1, rem = t & ((1 << S1) - 1);
        const long base = (long)t + (long)CHT * a * (a - 1) + (long)a * rem;
        float* P = part + ((base + c) * 4 + b) * SLOT_F;
        #pragma unroll
        for (int rg = 0; rg < 4; ++rg) {
            f32x4 v0, v1;
            #pragma unroll
            for (int rr = 0; rr < 4; ++rr) { v0[rr] = o0[4 * rg + rr]; v1[rr] = o1[4 * rg + rr]; }
            *(f32x4*)(P + (rg * 64 + lane) * 4)       = v0;
            *(f32x4*)(P + ((4 + rg) * 64 + lane) * 4) = v1;
        }
        if (hi == 0) { P[2048 + ql] = m_run; P[2080 + ql] = l_run; }
    }
}

// ============ Phase 2: merge nch partials per strip, transpose, store =======
__global__ __launch_bounds__(256) void
attn_merge32(const float* __restrict__ part, float* __restrict__ O)
{
    __shared__ float lt[32][65];
    const int b = blockIdx.x & 3;
    const int t = blockIdx.x >> 2;
    const int nch = (t >> S1) + 1;
    const int a = t >> S1, rem = t & ((1 << S1) - 1);
    const long base = ((long)t + (long)CHT * a * (a - 1) + (long)a * rem) * 4 + b;

    const int w = threadIdx.x >> 6;      // wave 0..3 owns chunks {w, w+4}
    const int lane = threadIdx.x & 63;
    const int ql = lane & 31, hi = lane >> 5;

    float mstar = -1e30f;
    for (int c = 0; c < nch; ++c)
        mstar = fmaxf(mstar, part[(base + 4 * c) * SLOT_F + 2048 + ql]);

    f32x4 acc0 = (f32x4){0.f, 0.f, 0.f, 0.f};
    f32x4 acc1 = (f32x4){0.f, 0.f, 0.f, 0.f};
    float ls = 0.f;
    for (int c = 0; c < nch; ++c) {
        const float* P = part + (base + 4 * c) * SLOT_F;
        const float wgt = exp2f(P[2048 + ql] - mstar);
        ls += wgt * P[2080 + ql];
        acc0 += wgt * *(const f32x4*)(P + (w * 64 + lane) * 4);
        acc1 += wgt * *(const f32x4*)(P + ((w + 4) * 64 + lane) * 4);
    }
    const float inv = 1.0f / ls;
    #pragma unroll
    for (int rr = 0; rr < 4; ++rr) {
        const int d = rr + 8 * w + 4 * hi;
        lt[ql][d]      = acc0[rr] * inv;
        lt[ql][32 + d] = acc1[rr] * inv;
    }
    __syncthreads();
    {
        const int q = threadIdx.x >> 3;
        const int dc = (threadIdx.x & 7) * 8;
        f32x4 r0, r1;
        #pragma unroll
        for (int j = 0; j < 4; ++j) { r0[j] = lt[q][dc + j]; r1[j] = lt[q][dc + 4 + j]; }
        float* Ob = O + ((long)b * SS + t * 32 + q) * DD + dc;
        *(f32x4*)Ob       = r0;
        *(f32x4*)(Ob + 4) = r1;
    }
}

// ============ Last-resort fallback (round-3 kernel, no workspace) ===========
__global__ __launch_bounds__(512, 4) void
attn_fb(const float* __restrict__ Q, const float* __restrict__ K,
        const float* __restrict__ V, float* __restrict__ O)
{
    __shared__ float mbuf[4][16 * 68];
    __shared__ float smM[4][16];
    __shared__ float smL[4][16];
    const int tid = threadIdx.x, w = tid >> 6, lane = tid & 63;
    const int m = lane & 15, g = lane >> 4;
    const int idx = blockIdx.x, t = 255 - (idx >> 2), b = idx & 3, q0 = t * 16;
    const float* Kb0 = K + (long)b * SS * DD;
    const float* Vb0 = V + (long)b * SS * DD;
    typedef __attribute__((ext_vector_type(4))) float f4;
    s16x8 qf[2];
    {
        const float* qrow = Q + ((long)b * SS + q0 + m) * DD + g * 8;
        #pragma unroll
        for (int kst = 0; kst < 2; ++kst) {
            f4 x0 = *(const f4*)(qrow + kst * 32);
            f4 x1 = *(const f4*)(qrow + kst * 32 + 4);
            frag_u f;
            f.u[0] = pack_bf16(x0[0] * QSCALE, x0[1] * QSCALE);
            f.u[1] = pack_bf16(x0[2] * QSCALE, x0[3] * QSCALE);
            f.u[2] = pack_bf16(x1[0] * QSCALE, x1[1] * QSCALE);
            f.u[3] = pack_bf16(x1[2] * QSCALE, x1[3] * QSCALE);
            qf[kst] = f.s;
        }
    }
    f4 o[4];
    #pragma unroll
    for (int dt = 0; dt < 4; ++dt) o[dt] = (f4){0.f, 0.f, 0.f, 0.f};
    float m_run = -1e30f, l_run = 0.f;
    const int ntiles = (q0 >> 6) + 1, q_g = q0 + m;
    for (int tile = w; tile < ntiles; tile += 8) {
        const int kvbase = tile * 64;
        f4 st[4];
        #pragma unroll
        for (int mt = 0; mt < 4; ++mt) {
            st[mt] = (f4){0.f, 0.f, 0.f, 0.f};
            const float* kr = Kb0 + (long)(kvbase + mt * 16 + m) * DD + g * 8;
            #pragma unroll
            for (int kst = 0; kst < 2; ++kst) {
                f4 x0 = *(const f4*)(kr + kst * 32);
                f4 x1 = *(const f4*)(kr + kst * 32 + 4);
                frag_u kf;
                kf.u[0] = pack_bf16(x0[0], x0[1]);
                kf.u[1] = pack_bf16(x0[2], x0[3]);
                kf.u[2] = pack_bf16(x1[0], x1[1]);
                kf.u[3] = pack_bf16(x1[2], x1[3]);
                st[mt] = __builtin_amdgcn_mfma_f32_16x16x32_bf16(kf.s, qf[kst], st[mt], 0, 0, 0);
            }
        }
        if (tile == ntiles - 1) {
            #pragma unroll
            for (int mt = 0; mt < 4; ++mt)
                #pragma unroll
                for (int r = 0; r < 4; ++r)
                    if (kvbase + mt * 16 + g * 4 + r > q_g) st[mt][r] = -1e9f;
        }
        float tm = st[0][0];
        #pragma unroll
        for (int mt = 0; mt < 4; ++mt)
            #pragma unroll
            for (int r = 0; r < 4; ++r) tm = fmaxf(tm, st[mt][r]);
        tm = fmaxf(tm, __shfl_xor(tm, 16));
        tm = fmaxf(tm, __shfl_xor(tm, 32));
        const float mnew = fmaxf(m_run, tm);
        const float alpha = exp2f(m_run - mnew);
        float rs = 0.f;
        #pragma unroll
        for (int mt = 0; mt < 4; ++mt)
            #pragma unroll
            for (int r = 0; r < 4; ++r) {
                const float e = exp2f(st[mt][r] - mnew);
                st[mt][r] = e; rs += e;
            }
        rs += __shfl_xor(rs, 16);
        rs += __shfl_xor(rs, 32);
        l_run = l_run * alpha + rs; m_run = mnew;
        unsigned pk[4][2];
        #pragma unroll
        for (int mt = 0; mt < 4; ++mt) {
            pk[mt][0] = pack_bf16(st[mt][0], st[mt][1]);
            pk[mt][1] = pack_bf16(st[mt][2], st[mt][3]);
        }
        float av[4];
        #pragma unroll
        for (int r = 0; r < 4; ++r) av[r] = __shfl(alpha, 4 * g + r);
        #pragma unroll
        for (int dt = 0; dt < 4; ++dt)
            #pragma unroll
            for (int r = 0; r < 4; ++r) o[dt][r] *= av[r];
        #pragma unroll
        for (int kst = 0; kst < 2; ++kst) {
            frag_u pa;
            #pragma unroll
            for (int ww = 0; ww < 4; ++ww) {
                const int srcl = m + 16 * (2 * (g & 1) + (ww >> 1));
                const int v0 = __shfl((int)pk[2 * kst][ww & 1], srcl);
                const int v1 = __shfl((int)pk[2 * kst + 1][ww & 1], srcl);
                pa.u[ww] = (unsigned)((g & 2) ? v1 : v0);
            }
            const float* vcol = Vb0 + (long)(kvbase + kst * 32 + g * 8) * DD + m;
            #pragma unroll
            for (int dt = 0; dt < 4; ++dt) {
                const float* vc = vcol + dt * 16;
                frag_u vb;
                #pragma unroll
                for (int jj = 0; jj < 4; ++jj)
                    vb.u[jj] = pack_bf16(vc[(2 * jj) * DD], vc[(2 * jj + 1) * DD]);
                o[dt] = __builtin_amdgcn_mfma_f32_16x16x32_bf16(pa.s, vb.s, o[dt], 0, 0, 0);
            }
        }
    }
    for (int half = 4; half >= 1; half >>= 1) {
        if (w >= half && w < 2 * half) {
            const int slot = w - half;
            if (g == 0) { smM[slot][m] = m_run; smL[slot][m] = l_run; }
            #pragma unroll
            for (int dt = 0; dt < 4; ++dt)
                #pragma unroll
                for (int r = 0; r < 4; ++r)
                    mbuf[slot][(4 * g + r) * 68 + 16 * dt + m] = o[dt][r];
        }
        __syncthreads();
        if (w < half) {
            const float m2 = smM[w][m], l2 = smL[w][m];
            const float mn = fmaxf(m_run, m2);
            const float a1 = exp2f(m_run - mn), a2 = exp2f(m2 - mn);
            l_run = l_run * a1 + l2 * a2; m_run = mn;
            float av1[4], av2[4];
            #pragma unroll
            for (int r = 0; r < 4; ++r) {
                av1[r] = __shfl(a1, 4 * g + r);
                av2[r] = __shfl(a2, 4 * g + r);
            }
            #pragma unroll
            for (int dt = 0; dt < 4; ++dt)
                #pragma unroll
                for (int r = 0; r < 4; ++r)
                    o[dt][r] = o[dt][r] * av1[r] +
                               mbuf[w][(4 * g + r) * 68 + 16 * dt + m] * av2[r];
        }
        __syncthreads();
    }
    if (w == 0) {
        float lv[4];
        #pragma unroll
        for (int r = 0; r < 4; ++r) lv[r] = 1.0f / __shfl(l_run, 4 * g + r);
        float* Ob = O + ((long)b * SS + q0) * DD;
        #pragma unroll
        for (int dt = 0; dt < 4; ++dt)
            #pragma unroll
            for (int r = 0; r < 4; ++r)
                Ob[(4 * g + r) * DD + dt * 16 + m] = o[dt][r] * lv[r];
    }
}

extern "C" void kernel_launch(void* const* d_in, const int* in_sizes, int n_in,
                              void* d_out, int out_size, void* d_ws, size_t ws_size,
                              hipStream_t stream) {
    const float* Q = (const float*)d_in[0];
    const float* K = (const float*)d_in[1];
    const float* V = (const float*)d_in[2];
    float* O = (float*)d_out;

    const size_t tensor_b = (size_t)BB * SS * DD * sizeof(u16);   // 2 MiB each
    const size_t conv_b   = 2 * tensor_b;
    const size_t part_b   = (size_t)4352 * SLOT_F * sizeof(float);

    if (ws_size >= conv_b + part_b) {
        u16* Kf = (u16*)d_ws;
        u16* Vf = (u16*)((char*)d_ws + tensor_b);
        float* part = (float*)((char*)d_ws + conv_b);
        conv_kf<<<dim3(512), dim3(256), 0, stream>>>(K, Kf);
        conv_vf<<<dim3(256), dim3(256), 0, stream>>>(V, Vf);
        attn_part32 <<<dim3(2048), dim3(256), 0, stream>>>(Q, Kf, Vf, part);
        attn_merge32<<<dim3(512),  dim3(256), 0, stream>>>(part, O);
    } else {
        attn_fb<<<dim3(BB * (SS / 16)), dim3(512), 0, stream>>>(Q, K, V, O);
    }
}

// Round 9
// 47.207 us; speedup vs baseline: 2.0437x; 1.0963x over previous
//
#include <hip/hip_runtime.h>

#define BB 4
#define SS 4096
#define DD 64
// scale = 1/sqrt(4096), with log2(e) folded in so softmax runs in exp2 domain
#define QSCALE (0.015625f * 1.44269504088896f)

typedef __attribute__((ext_vector_type(4)))  float f32x4;
typedef __attribute__((ext_vector_type(16))) float f32x16;
typedef __attribute__((ext_vector_type(8)))  short s16x8;
typedef unsigned short u16;

union frag_u { unsigned u[4]; s16x8 s; };

#define SLOT_F 2112   // 8 groups x 64 lanes x 4 f32 (2048) + m[32] + l[32]
#define S1 3
#define CHT 4

// Round-half-up pack of two f32 into (lo,hi) bf16 pair.
__device__ __forceinline__ unsigned pack_bf16(float lo, float hi) {
    union { float f; unsigned u; } a, b; a.f = lo; b.f = hi;
    return __builtin_amdgcn_perm(b.u + 0x8000u, a.u + 0x8000u, 0x07060302u);
}

__device__ __forceinline__ void pl32swap(unsigned &a, unsigned &b) {
    asm volatile("v_permlane32_swap_b32 %0, %1" : "+v"(a), "+v"(b));
}

// ---- fused prep: blocks 0..511 do K->Kf, 512..767 do V->Vf ----
// Kf[b][tile][kt][kst][lane] (8 bf16); Vf[b][tile][dt][ks][lane] (8 bf16, V^T)
__global__ __launch_bounds__(256) void conv_fused(const float* __restrict__ K,
                                                  const float* __restrict__ V,
                                                  u16* __restrict__ Kf,
                                                  u16* __restrict__ Vf) {
    if (blockIdx.x < 512) {
        const int g    = blockIdx.x * 256 + threadIdx.x;
        const int lane = g & 63, kst = (g >> 6) & 3, kt = (g >> 8) & 1;
        const int tile = (g >> 9) & 63, b = g >> 15;
        const int ql = lane & 31, hi = lane >> 5;
        const long src = ((long)b * SS + tile * 64 + kt * 32 + ql) * DD + kst * 16 + hi * 8;
        f32x4 x0 = *(const f32x4*)(K + src);
        f32x4 x1 = *(const f32x4*)(K + src + 4);
        frag_u f;
        f.u[0] = pack_bf16(x0[0], x0[1]);
        f.u[1] = pack_bf16(x0[2], x0[3]);
        f.u[2] = pack_bf16(x1[0], x1[1]);
        f.u[3] = pack_bf16(x1[2], x1[3]);
        *(s16x8*)(Kf + (long)g * 8) = f.s;
    } else {
        __shared__ u16 tl[64][72];       // [d][s_local]
        const int bid = blockIdx.x - 512;
        const int b = bid >> 6;
        const int tile = bid & 63;
        const int tid = threadIdx.x;
        const float* Vb = V + ((long)b * SS + tile * 64) * DD;
        {
            const int kk = tid >> 4;
            const int d4 = (tid & 15) * 4;
            #pragma unroll
            for (int p = 0; p < 4; ++p) {
                const int k = kk + p * 16;
                f32x4 v = *(const f32x4*)(Vb + k * DD + d4);
                #pragma unroll
                for (int c = 0; c < 4; ++c) {
                    union { float f; unsigned u; } x; x.f = v[c];
                    tl[d4 + c][k] = (u16)((x.u + 0x8000u) >> 16);
                }
            }
        }
        __syncthreads();
        {
            const int ks = tid >> 6, lane = tid & 63;
            const int ql = lane & 31, hi = lane >> 5;
            const int s0 = ks * 16 + hi * 8;
            u16* out = Vf + (((long)(b * 64 + tile) * 2) * 4 + ks) * 64 * 8 + lane * 8;
            #pragma unroll
            for (int dt = 0; dt < 2; ++dt) {
                const int row = dt * 32 + ql;
                frag_u f;
                #pragma unroll
                for (int j = 0; j < 4; ++j)
                    f.u[j] = (unsigned)tl[row][s0 + 2 * j] |
                             ((unsigned)tl[row][s0 + 2 * j + 1] << 16);
                *(s16x8*)(out + (long)dt * 4 * 64 * 8) = f.s;
            }
        }
    }
}

// ============ Phase 1: block = (b, strip-group, chunk); wave = strip ========
// 4 waves of a block share batch b and KV chunk c -> L1 reuse; strips
// t = tg*4 + w. Within a group nch is uniform -> no idle waves.
// XCD placement: bid&7 selects XCD; batch b owns XCDs {2b, 2b+1}.
__global__ __launch_bounds__(256, 3) void
attn_part32(const float* __restrict__ Q, const u16* __restrict__ Kf,
            const u16* __restrict__ Vf, float* __restrict__ part)
{
    const int bid = blockIdx.x;
    const int xcd = bid & 7;
    const int pos = bid >> 3;
    const int b   = xcd >> 1;
    const int G   = pos * 2 + (xcd & 1);      // 0..271 within batch

    // invert G -> (tg, c): S(2a)=a^2+a, S(2a+1)=(a+1)^2
    int r = (int)sqrtf((float)G);
    while ((r + 1) * (r + 1) <= G) ++r;
    while (r * r > G) --r;
    int tg, c;
    if (G < r * r + r) { tg = 2 * r - 1; c = G - r * r; }
    else               { tg = 2 * r;     c = G - r * r - r; }

    const int w    = threadIdx.x >> 6;
    const int t    = tg * 4 + w;
    const int lane = threadIdx.x & 63;
    const int ql = lane & 31, hi = lane >> 5, hi8 = hi * 8;
    const int q0 = t * 32;
    const int q_g = q0 + ql;
    const int ntiles = (t >> 1) + 1;

    // ---- Q B-frags: B[d = kst*16 + hi*8 + j][q = ql], scale folded ----
    s16x8 qf[4];
    {
        const float* qrow = Q + ((long)b * SS + q_g) * DD + hi8;
        #pragma unroll
        for (int kst = 0; kst < 4; ++kst) {
            f32x4 x0 = *(const f32x4*)(qrow + kst * 16);
            f32x4 x1 = *(const f32x4*)(qrow + kst * 16 + 4);
            frag_u f;
            f.u[0] = pack_bf16(x0[0] * QSCALE, x0[1] * QSCALE);
            f.u[1] = pack_bf16(x0[2] * QSCALE, x0[3] * QSCALE);
            f.u[2] = pack_bf16(x1[0] * QSCALE, x1[1] * QSCALE);
            f.u[3] = pack_bf16(x1[2] * QSCALE, x1[3] * QSCALE);
            qf[kst] = f.s;
        }
    }

    f32x16 o0, o1;
    #pragma unroll
    for (int r2 = 0; r2 < 16; ++r2) { o0[r2] = 0.f; o1[r2] = 0.f; }
    float m_run = -1e30f, l_run = 0.f;

    const int tlo = c * CHT;
    const int thi = min(ntiles, tlo + CHT);

    for (int tile = tlo; tile < thi; ++tile) {
        // ---- fully-coalesced fragment loads; 4 waves share -> L1 hits ----
        const u16* Kt = Kf + (long)((b * 64 + tile) * 4096) + lane * 8;
        const u16* Vt = Vf + (long)((b * 64 + tile) * 4096) + lane * 8;
        s16x8 kf[2][4], vf[2][4];
        #pragma unroll
        for (int kt = 0; kt < 2; ++kt)
            #pragma unroll
            for (int kst = 0; kst < 4; ++kst)
                kf[kt][kst] = *(const s16x8*)(Kt + (kt * 4 + kst) * 512);
        #pragma unroll
        for (int dt = 0; dt < 2; ++dt)
            #pragma unroll
            for (int ks = 0; ks < 4; ++ks)
                vf[dt][ks] = *(const s16x8*)(Vt + (dt * 4 + ks) * 512);

        // ---- S^T = K · Q^T : col=q(=ql), row=k = kt*32+(r&3)+8*(r>>2)+4*hi
        f32x16 st0, st1;
        #pragma unroll
        for (int r2 = 0; r2 < 16; ++r2) { st0[r2] = 0.f; st1[r2] = 0.f; }
        __builtin_amdgcn_s_setprio(1);
        #pragma unroll
        for (int kst = 0; kst < 4; ++kst) {
            st0 = __builtin_amdgcn_mfma_f32_32x32x16_bf16(kf[0][kst], qf[kst], st0, 0, 0, 0);
            st1 = __builtin_amdgcn_mfma_f32_32x32x16_bf16(kf[1][kst], qf[kst], st1, 0, 0, 0);
        }
        __builtin_amdgcn_s_setprio(0);

        const int kvb = tile * 64;
        if (tile == ntiles - 1) {
            #pragma unroll
            for (int r2 = 0; r2 < 16; ++r2) {
                const int crow = (r2 & 3) + 8 * (r2 >> 2) + 4 * hi;
                if (kvb + crow > q_g)      st0[r2] = -1e9f;
                if (kvb + 32 + crow > q_g) st1[r2] = -1e9f;
            }
        }

        // ---- online softmax: lane owns row q_g; 1 cross-lane shfl ----
        float tm = -1e30f;
        #pragma unroll
        for (int r2 = 0; r2 < 16; ++r2) { tm = fmaxf(tm, st0[r2]); tm = fmaxf(tm, st1[r2]); }
        tm = fmaxf(tm, __shfl_xor(tm, 32));
        const float mnew  = fmaxf(m_run, tm);
        const float alpha = exp2f(m_run - mnew);
        float rs = 0.f;
        #pragma unroll
        for (int r2 = 0; r2 < 16; ++r2) {
            st0[r2] = exp2f(st0[r2] - mnew); rs += st0[r2];
            st1[r2] = exp2f(st1[r2] - mnew); rs += st1[r2];
        }
        rs += __shfl_xor(rs, 32);
        l_run = l_run * alpha + rs;
        m_run = mnew;

        // ---- P -> bf16 B-frags via permlane32_swap ----
        frag_u pf[4];
        #pragma unroll
        for (int kt = 0; kt < 2; ++kt) {
            unsigned wd[8];
            #pragma unroll
            for (int j = 0; j < 8; ++j)
                wd[j] = kt == 0 ? pack_bf16(st0[2 * j], st0[2 * j + 1])
                                : pack_bf16(st1[2 * j], st1[2 * j + 1]);
            unsigned a0 = wd[0], b0 = wd[2]; pl32swap(a0, b0);
            unsigned a1 = wd[1], b1 = wd[3]; pl32swap(a1, b1);
            pf[2 * kt].u[0] = a0; pf[2 * kt].u[1] = a1;
            pf[2 * kt].u[2] = b0; pf[2 * kt].u[3] = b1;
            unsigned a2 = wd[4], b2 = wd[6]; pl32swap(a2, b2);
            unsigned a3 = wd[5], b3 = wd[7]; pl32swap(a3, b3);
            pf[2 * kt + 1].u[0] = a2; pf[2 * kt + 1].u[1] = a3;
            pf[2 * kt + 1].u[2] = b2; pf[2 * kt + 1].u[3] = b3;
        }

        // ---- rescale O^T (col=q -> lane-local alpha) ----
        #pragma unroll
        for (int r2 = 0; r2 < 16; ++r2) { o0[r2] *= alpha; o1[r2] *= alpha; }

        // ---- O^T += V^T · P^T ----
        __builtin_amdgcn_s_setprio(1);
        #pragma unroll
        for (int ks = 0; ks < 4; ++ks) {
            o0 = __builtin_amdgcn_mfma_f32_32x32x16_bf16(vf[0][ks], pf[ks].s, o0, 0, 0, 0);
            o1 = __builtin_amdgcn_mfma_f32_32x32x16_bf16(vf[1][ks], pf[ks].s, o1, 0, 0, 0);
        }
        __builtin_amdgcn_s_setprio(0);
    }

    // ---- write partial, accumulator-lane order (fully coalesced) ----
    {
        const int a = t >> S1, rem = t & ((1 << S1) - 1);
        const long base = (long)t + (long)CHT * a * (a - 1) + (long)a * rem;
        float* P = part + ((base + c) * 4 + b) * SLOT_F;
        #pragma unroll
        for (int rg = 0; rg < 4; ++rg) {
            f32x4 v0, v1;
            #pragma unroll
            for (int rr = 0; rr < 4; ++rr) { v0[rr] = o0[4 * rg + rr]; v1[rr] = o1[4 * rg + rr]; }
            *(f32x4*)(P + (rg * 64 + lane) * 4)       = v0;
            *(f32x4*)(P + ((4 + rg) * 64 + lane) * 4) = v1;
        }
        if (hi == 0) { P[2048 + ql] = m_run; P[2080 + ql] = l_run; }
    }
}

// ============ Phase 2: merge nch partials per strip, transpose, store =======
__global__ __launch_bounds__(256) void
attn_merge32(const float* __restrict__ part, float* __restrict__ O)
{
    __shared__ float lt[32][65];
    const int b = blockIdx.x & 3;
    const int t = blockIdx.x >> 2;
    const int nch = (t >> S1) + 1;
    const int a = t >> S1, rem = t & ((1 << S1) - 1);
    const long base = ((long)t + (long)CHT * a * (a - 1) + (long)a * rem) * 4 + b;

    const int w = threadIdx.x >> 6;      // wave 0..3 owns d-groups {w, w+4}
    const int lane = threadIdx.x & 63;
    const int ql = lane & 31, hi = lane >> 5;

    float mstar = -1e30f;
    for (int c = 0; c < nch; ++c)
        mstar = fmaxf(mstar, part[(base + 4 * c) * SLOT_F + 2048 + ql]);

    f32x4 acc0 = (f32x4){0.f, 0.f, 0.f, 0.f};
    f32x4 acc1 = (f32x4){0.f, 0.f, 0.f, 0.f};
    float ls = 0.f;
    for (int c = 0; c < nch; ++c) {
        const float* P = part + (base + 4 * c) * SLOT_F;
        const float wgt = exp2f(P[2048 + ql] - mstar);
        ls += wgt * P[2080 + ql];
        acc0 += wgt * *(const f32x4*)(P + (w * 64 + lane) * 4);
        acc1 += wgt * *(const f32x4*)(P + ((w + 4) * 64 + lane) * 4);
    }
    const float inv = 1.0f / ls;
    #pragma unroll
    for (int rr = 0; rr < 4; ++rr) {
        const int d = rr + 8 * w + 4 * hi;
        lt[ql][d]      = acc0[rr] * inv;
        lt[ql][32 + d] = acc1[rr] * inv;
    }
    __syncthreads();
    {
        const int q = threadIdx.x >> 3;
        const int dc = (threadIdx.x & 7) * 8;
        f32x4 r0, r1;
        #pragma unroll
        for (int j = 0; j < 4; ++j) { r0[j] = lt[q][dc + j]; r1[j] = lt[q][dc + 4 + j]; }
        float* Ob = O + ((long)b * SS + t * 32 + q) * DD + dc;
        *(f32x4*)Ob       = r0;
        *(f32x4*)(Ob + 4) = r1;
    }
}

// ============ Last-resort fallback (round-3 kernel, no workspace) ===========
__global__ __launch_bounds__(512, 4) void
attn_fb(const float* __restrict__ Q, const float* __restrict__ K,
        const float* __restrict__ V, float* __restrict__ O)
{
    __shared__ float mbuf[4][16 * 68];
    __shared__ float smM[4][16];
    __shared__ float smL[4][16];
    const int tid = threadIdx.x, w = tid >> 6, lane = tid & 63;
    const int m = lane & 15, g = lane >> 4;
    const int idx = blockIdx.x, t = 255 - (idx >> 2), b = idx & 3, q0 = t * 16;
    const float* Kb0 = K + (long)b * SS * DD;
    const float* Vb0 = V + (long)b * SS * DD;
    typedef __attribute__((ext_vector_type(4))) float f4;
    s16x8 qf[2];
    {
        const float* qrow = Q + ((long)b * SS + q0 + m) * DD + g * 8;
        #pragma unroll
        for (int kst = 0; kst < 2; ++kst) {
            f4 x0 = *(const f4*)(qrow + kst * 32);
            f4 x1 = *(const f4*)(qrow + kst * 32 + 4);
            frag_u f;
            f.u[0] = pack_bf16(x0[0] * QSCALE, x0[1] * QSCALE);
            f.u[1] = pack_bf16(x0[2] * QSCALE, x0[3] * QSCALE);
            f.u[2] = pack_bf16(x1[0] * QSCALE, x1[1] * QSCALE);
            f.u[3] = pack_bf16(x1[2] * QSCALE, x1[3] * QSCALE);
            qf[kst] = f.s;
        }
    }
    f4 o[4];
    #pragma unroll
    for (int dt = 0; dt < 4; ++dt) o[dt] = (f4){0.f, 0.f, 0.f, 0.f};
    float m_run = -1e30f, l_run = 0.f;
    const int ntiles = (q0 >> 6) + 1, q_g = q0 + m;
    for (int tile = w; tile < ntiles; tile += 8) {
        const int kvbase = tile * 64;
        f4 st[4];
        #pragma unroll
        for (int mt = 0; mt < 4; ++mt) {
            st[mt] = (f4){0.f, 0.f, 0.f, 0.f};
            const float* kr = Kb0 + (long)(kvbase + mt * 16 + m) * DD + g * 8;
            #pragma unroll
            for (int kst = 0; kst < 2; ++kst) {
                f4 x0 = *(const f4*)(kr + kst * 32);
                f4 x1 = *(const f4*)(kr + kst * 32 + 4);
                frag_u kf;
                kf.u[0] = pack_bf16(x0[0], x0[1]);
                kf.u[1] = pack_bf16(x0[2], x0[3]);
                kf.u[2] = pack_bf16(x1[0], x1[1]);
                kf.u[3] = pack_bf16(x1[2], x1[3]);
                st[mt] = __builtin_amdgcn_mfma_f32_16x16x32_bf16(kf.s, qf[kst], st[mt], 0, 0, 0);
            }
        }
        if (tile == ntiles - 1) {
            #pragma unroll
            for (int mt = 0; mt < 4; ++mt)
                #pragma unroll
                for (int r = 0; r < 4; ++r)
                    if (kvbase + mt * 16 + g * 4 + r > q_g) st[mt][r] = -1e9f;
        }
        float tm = st[0][0];
        #pragma unroll
        for (int mt = 0; mt < 4; ++mt)
            #pragma unroll
            for (int r = 0; r < 4; ++r) tm = fmaxf(tm, st[mt][r]);
        tm = fmaxf(tm, __shfl_xor(tm, 16));
        tm = fmaxf(tm, __shfl_xor(tm, 32));
        const float mnew = fmaxf(m_run, tm);
        const float alpha = exp2f(m_run - mnew);
        float rs = 0.f;
        #pragma unroll
        for (int mt = 0; mt < 4; ++mt)
            #pragma unroll
            for (int r = 0; r < 4; ++r) {
                const float e = exp2f(st[mt][r] - mnew);
                st[mt][r] = e; rs += e;
            }
        rs += __shfl_xor(rs, 16);
        rs += __shfl_xor(rs, 32);
        l_run = l_run * alpha + rs; m_run = mnew;
        unsigned pk[4][2];
        #pragma unroll
        for (int mt = 0; mt < 4; ++mt) {
            pk[mt][0] = pack_bf16(st[mt][0], st[mt][1]);
            pk[mt][1] = pack_bf16(st[mt][2], st[mt][3]);
        }
        float av[4];
        #pragma unroll
        for (int r = 0; r < 4; ++r) av[r] = __shfl(alpha, 4 * g + r);
        #pragma unroll
        for (int dt = 0; dt < 4; ++dt)
            #pragma unroll
            for (int r = 0; r < 4; ++r) o[dt][r] *= av[r];
        #pragma unroll
        for (int kst = 0; kst < 2; ++kst) {
            frag_u pa;
            #pragma unroll
            for (int ww = 0; ww < 4; ++ww) {
                const int srcl = m + 16 * (2 * (g & 1) + (ww >> 1));
                const int v0 = __shfl((int)pk[2 * kst][ww & 1], srcl);
                const int v1 = __shfl((int)pk[2 * kst + 1][ww & 1], srcl);
                pa.u[ww] = (unsigned)((g & 2) ? v1 : v0);
            }
            const float* vcol = Vb0 + (long)(kvbase + kst * 32 + g * 8) * DD + m;
            #pragma unroll
            for (int dt = 0; dt < 4; ++dt) {
                const float* vc = vcol + dt * 16;
                frag_u vb;
                #pragma unroll
                for (int jj = 0; jj < 4; ++jj)
                    vb.u[jj] = pack_bf16(vc[(2 * jj) * DD], vc[(2 * jj + 1) * DD]);
                o[dt] = __builtin_amdgcn_mfma_f32_16x16x32_bf16(pa.s, vb.s, o[dt], 0, 0, 0);
            }
        }
    }
    for (int half = 4; half >= 1; half >>= 1) {
        if (w >= half && w < 2 * half) {
            const int slot = w - half;
            if (g == 0) { smM[slot][m] = m_run; smL[slot][m] = l_run; }
            #pragma unroll
            for (int dt = 0; dt < 4; ++dt)
                #pragma unroll
                for (int r = 0; r < 4; ++r)
                    mbuf[slot][(4 * g + r) * 68 + 16 * dt + m] = o[dt][r];
        }
        __syncthreads();
        if (w < half) {
            const float m2 = smM[w][m], l2 = smL[w][m];
            const float mn = fmaxf(m_run, m2);
            const float a1 = exp2f(m_run - mn), a2 = exp2f(m2 - mn);
            l_run = l_run * a1 + l2 * a2; m_run = mn;
            float av1[4], av2[4];
            #pragma unroll
            for (int r = 0; r < 4; ++r) {
                av1[r] = __shfl(a1, 4 * g + r);
                av2[r] = __shfl(a2, 4 * g + r);
            }
            #pragma unroll
            for (int dt = 0; dt < 4; ++dt)
                #pragma unroll
                for (int r = 0; r < 4; ++r)
                    o[dt][r] = o[dt][r] * av1[r] +
                               mbuf[w][(4 * g + r) * 68 + 16 * dt + m] * av2[r];
        }
        __syncthreads();
    }
    if (w == 0) {
        float lv[4];
        #pragma unroll
        for (int r = 0; r < 4; ++r) lv[r] = 1.0f / __shfl(l_run, 4 * g + r);
        float* Ob = O + ((long)b * SS + q0) * DD;
        #pragma unroll
        for (int dt = 0; dt < 4; ++dt)
            #pragma unroll
            for (int r = 0; r < 4; ++r)
                Ob[(4 * g + r) * DD + dt * 16 + m] = o[dt][r] * lv[r];
    }
}

extern "C" void kernel_launch(void* const* d_in, const int* in_sizes, int n_in,
                              void* d_out, int out_size, void* d_ws, size_t ws_size,
                              hipStream_t stream) {
    const float* Q = (const float*)d_in[0];
    const float* K = (const float*)d_in[1];
    const float* V = (const float*)d_in[2];
    float* O = (float*)d_out;

    const size_t tensor_b = (size_t)BB * SS * DD * sizeof(u16);   // 2 MiB each
    const size_t conv_b   = 2 * tensor_b;
    const size_t part_b   = (size_t)4352 * SLOT_F * sizeof(float);

    if (ws_size >= conv_b + part_b) {
        u16* Kf = (u16*)d_ws;
        u16* Vf = (u16*)((char*)d_ws + tensor_b);
        float* part = (float*)((char*)d_ws + conv_b);
        conv_fused  <<<dim3(768),  dim3(256), 0, stream>>>(K, V, Kf, Vf);
        attn_part32 <<<dim3(1088), dim3(256), 0, stream>>>(Q, Kf, Vf, part);
        attn_merge32<<<dim3(512),  dim3(256), 0, stream>>>(part, O);
    } else {
        attn_fb<<<dim3(BB * (SS / 16)), dim3(512), 0, stream>>>(Q, K, V, O);
    }
}